// Round 1
// baseline (628.071 us; speedup 1.0000x reference)
//
#include <hip/hip_runtime.h>
#include <hip/hip_bf16.h>

typedef __attribute__((ext_vector_type(8))) short short8;
typedef __attribute__((ext_vector_type(4))) float floatx4;

#define B_N   4
#define C_INN 256
#define T_N   8
#define H_N   56
#define W_N   56
#define C_OUTN 256
#define HW_N  (H_N * W_N)
#define NTAP  9

// LDS strides padded to 40 bf16 (80 B) -> conflict-free ds_read_b128
#define LDA_S 40
#define LDX_S 40

// -------- prep: weight (C_OUT, C_IN, 1, 3, 3) fp32 -> wb[c_out][tap][c_in] bf16 --------
__global__ void prep_weight(const float* __restrict__ w, __hip_bfloat16* __restrict__ wb) {
    int idx = blockIdx.x * blockDim.x + threadIdx.x;   // over C_OUT*9*C_IN
    if (idx >= C_OUTN * NTAP * C_INN) return;
    int ci  = idx % C_INN;
    int tap = (idx / C_INN) % NTAP;
    int o   = idx / (NTAP * C_INN);
    wb[idx] = __float2bfloat16(w[(o * C_INN + ci) * NTAP + tap]);
}

// -------- main: implicit-GEMM conv, 128x128 tile, halo-shared taps --------
__global__ __launch_bounds__(256, 2) void tada_conv(
    const float* __restrict__ x, const float* __restrict__ alpha,
    const __hip_bfloat16* __restrict__ wb, const float* __restrict__ bias,
    float* __restrict__ out)
{
    __shared__ __hip_bfloat16 lA[128 * LDA_S];        // 10240 B
    __shared__ __hip_bfloat16 lX[6 * 34 * LDX_S];     // 16320 B

    const int tid   = threadIdx.x;
    const int mtile = blockIdx.x;          // 0..1   (c_out tile of 128)
    const int ntile = blockIdx.y;          // 0..27  (14 h-tiles x 2 w-tiles)
    const int bt    = blockIdx.z;          // 0..31
    const int b = bt >> 3, t = bt & 7;
    const int h0 = (ntile % 14) * 4;
    const int w0 = (ntile / 14) * 32;

    const int wave = tid >> 6, lane = tid & 63;
    const int wm = wave >> 1, wn = wave & 1;     // 2x2 waves, each 64x64
    const int col = lane & 15, quad = lane >> 4;

    floatx4 acc[4][4];
#pragma unroll
    for (int i = 0; i < 4; ++i)
#pragma unroll
        for (int j = 0; j < 4; ++j)
            acc[i][j] = (floatx4){0.f, 0.f, 0.f, 0.f};

    const long xbase = ((long)b * C_INN) * (T_N * HW_N) + (long)t * HW_N;
    const int  abase = b * C_INN * T_N + t;

    for (int cg = 0; cg < 8; ++cg) {
        __syncthreads();   // previous cg's X reads done
        // ---- stage X halo: 32 ci x 6 h x 34 w, alpha-scaled, bf16 ----
        for (int idx = tid; idx < 32 * 204; idx += 256) {
            int ci  = idx / 204;
            int rem = idx - ci * 204;
            int hi  = rem / 34;
            int wi  = rem - hi * 34;
            int hh = h0 - 1 + hi;
            int ww = w0 - 1 + wi;
            int cig = cg * 32 + ci;
            float v = 0.f;
            if ((unsigned)hh < (unsigned)H_N && (unsigned)ww < (unsigned)W_N) {
                v = x[xbase + (long)cig * (T_N * HW_N) + hh * W_N + ww]
                    * alpha[abase + cig * T_N];
            }
            lX[(hi * 34 + wi) * LDX_S + ci] = __float2bfloat16(v);
        }

        for (int tap = 0; tap < NTAP; ++tap) {
            __syncthreads();   // prev A reads done (and X staged on first tap)
            // ---- stage A: 128 rows (c_out) x 32 cols (c_in), bf16 ----
#pragma unroll
            for (int p = 0; p < 2; ++p) {
                int r = p * 64 + (tid >> 2);
                int c = (tid & 3) * 8;
                const short8 v = *(const short8*)(wb +
                    (((mtile * 128 + r) * NTAP + tap) * C_INN + cg * 32 + c));
                *(short8*)(lA + r * LDA_S + c) = v;
            }
            __syncthreads();   // A (and X) visible

            const int kh = tap / 3, kw = tap % 3;
            short8 af[4], bf[4];
#pragma unroll
            for (int mi = 0; mi < 4; ++mi)
                af[mi] = *(const short8*)(lA + (wm * 64 + mi * 16 + col) * LDA_S + quad * 8);
#pragma unroll
            for (int ni = 0; ni < 4; ++ni) {
                int g   = wn * 4 + ni;            // 16-pixel group 0..7
                int ph  = g >> 1;
                int pw0 = (g & 1) * 16;
                int px  = (ph + kh) * 34 + pw0 + col + kw;
                bf[ni] = *(const short8*)(lX + px * LDX_S + quad * 8);
            }
#pragma unroll
            for (int mi = 0; mi < 4; ++mi)
#pragma unroll
                for (int ni = 0; ni < 4; ++ni)
                    acc[mi][ni] = __builtin_amdgcn_mfma_f32_16x16x32_bf16(
                        af[mi], bf[ni], acc[mi][ni], 0, 0, 0);
        }
    }

    // ---- epilogue: bias + store (C/D layout: col=lane&15, row=quad*4+reg) ----
#pragma unroll
    for (int mi = 0; mi < 4; ++mi) {
        const floatx4 bv = *(const floatx4*)(bias + mtile * 128 + wm * 64 + mi * 16 + quad * 4);
#pragma unroll
        for (int ni = 0; ni < 4; ++ni) {
            int n  = wn * 64 + ni * 16 + col;
            int ph = n >> 5, pw = n & 31;
            if (w0 + pw < W_N) {
#pragma unroll
                for (int r = 0; r < 4; ++r) {
                    int m = mtile * 128 + wm * 64 + mi * 16 + quad * 4 + r;
                    out[(((long)b * C_OUTN + m) * T_N + t) * HW_N + (h0 + ph) * W_N + (w0 + pw)]
                        = acc[mi][ni][r] + bv[r];
                }
            }
        }
    }
}

extern "C" void kernel_launch(void* const* d_in, const int* in_sizes, int n_in,
                              void* d_out, int out_size, void* d_ws, size_t ws_size,
                              hipStream_t stream) {
    const float* x      = (const float*)d_in[0];
    const float* alpha  = (const float*)d_in[1];
    const float* weight = (const float*)d_in[2];
    const float* bias   = (const float*)d_in[3];
    float* out = (float*)d_out;

    __hip_bfloat16* wb = (__hip_bfloat16*)d_ws;   // C_OUT*9*C_IN bf16 = 1.18 MB

    int nprep = C_OUTN * NTAP * C_INN;
    prep_weight<<<(nprep + 255) / 256, 256, 0, stream>>>(weight, wb);

    dim3 grid(2, 28, 32);
    tada_conv<<<grid, 256, 0, stream>>>(x, alpha, wb, bias, out);
}

// Round 2
// 584.350 us; speedup vs baseline: 1.0748x; 1.0748x over previous
//
#include <hip/hip_runtime.h>
#include <hip/hip_bf16.h>

typedef __attribute__((ext_vector_type(8))) short short8;
typedef __attribute__((ext_vector_type(4))) float floatx4;

#define C_INN 256
#define T_N   8
#define H_N   56
#define W_N   56
#define C_OUTN 256
#define HW_N  (H_N * W_N)
#define THW   (T_N * HW_N)
#define NTAP  9
#define LDX_S 40   // bf16 elems per px row (32 + 8 pad); dw-stride 20 -> conflict-free

// -------- prep: weight (C_OUT, C_IN, 1, 3, 3) fp32 -> wb[c_out][tap][c_in] bf16 --------
__global__ void prep_weight(const float* __restrict__ w, __hip_bfloat16* __restrict__ wb) {
    int idx = blockIdx.x * blockDim.x + threadIdx.x;
    if (idx >= C_OUTN * NTAP * C_INN) return;
    int ci  = idx % C_INN;
    int tap = (idx / C_INN) % NTAP;
    int o   = idx / (NTAP * C_INN);
    wb[idx] = __float2bfloat16(w[(o * C_INN + ci) * NTAP + tap]);
}

// -------- main: implicit-GEMM conv; A from global (no LDS), X halo in LDS, 2 syncs/cg --------
__global__ __launch_bounds__(256, 2) void tada_conv(
    const float* __restrict__ x, const float* __restrict__ alpha,
    const __hip_bfloat16* __restrict__ wb, const float* __restrict__ bias,
    float* __restrict__ out)
{
    __shared__ __hip_bfloat16 lX[204 * LDX_S];   // 16320 B

    const int tid   = threadIdx.x;
    const int mtile = blockIdx.x;          // 0..1
    const int ntile = blockIdx.y;          // 0..27
    const int bt    = blockIdx.z;          // 0..31
    const int b = bt >> 3, t = bt & 7;
    const int h0 = (ntile % 14) * 4;
    const int w0 = (ntile / 14) * 32;

    const int wave = tid >> 6, lane = tid & 63;
    const int wm = wave >> 1, wn = wave & 1;     // 2x2 waves, each 64x64
    const int col = lane & 15, quad = lane >> 4;

    // staging decomposition: 8 ci-quads x 32 px-lanes (px-lane fast for coalescing)
    const int cil = tid >> 5;   // 0..7  -> ci group of 4
    const int pxl = tid & 31;   // 0..31

    floatx4 acc[4][4];
#pragma unroll
    for (int i = 0; i < 4; ++i)
#pragma unroll
        for (int j = 0; j < 4; ++j)
            acc[i][j] = (floatx4){0.f, 0.f, 0.f, 0.f};

    const long xbase = ((long)b * C_INN) * THW + (long)t * HW_N;
    const int  abase = b * C_INN * T_N + t;

    const __hip_bfloat16* wp0 = wb + ((long)(mtile * 128 + wm * 64 + col) * NTAP) * C_INN + quad * 8;

    for (int cg = 0; cg < 8; ++cg) {
        __syncthreads();   // previous cg's lX reads done
        {
            const int ci0 = cg * 32 + cil * 4;
            const float a0 = alpha[abase + (ci0 + 0) * T_N];
            const float a1 = alpha[abase + (ci0 + 1) * T_N];
            const float a2 = alpha[abase + (ci0 + 2) * T_N];
            const float a3 = alpha[abase + (ci0 + 3) * T_N];
            const float* xc = x + xbase + (long)ci0 * THW;
#pragma unroll
            for (int it = 0; it < 7; ++it) {
                int px = pxl + it * 32;
                if (px < 204) {
                    int hi = px / 34;
                    int wi = px - hi * 34;
                    int hh = h0 - 1 + hi;
                    int ww = w0 - 1 + wi;
                    float v0 = 0.f, v1 = 0.f, v2 = 0.f, v3 = 0.f;
                    if (((unsigned)hh < (unsigned)H_N) && ((unsigned)ww < (unsigned)W_N)) {
                        const float* xp = xc + hh * W_N + ww;
                        v0 = xp[0]       * a0;
                        v1 = xp[THW]     * a1;
                        v2 = xp[2 * THW] * a2;
                        v3 = xp[3 * THW] * a3;
                    }
                    union { __hip_bfloat16 h[4]; unsigned long long u; } pk;
                    pk.h[0] = __float2bfloat16(v0);
                    pk.h[1] = __float2bfloat16(v1);
                    pk.h[2] = __float2bfloat16(v2);
                    pk.h[3] = __float2bfloat16(v3);
                    *reinterpret_cast<unsigned long long*>(&lX[px * LDX_S + cil * 4]) = pk.u;
                }
            }
        }
        __syncthreads();   // lX staged

        const __hip_bfloat16* wp = wp0 + cg * 32;
#pragma unroll
        for (int kh = 0; kh < 3; ++kh) {
#pragma unroll
            for (int kw = 0; kw < 3; ++kw) {
                const int tap = kh * 3 + kw;
                short8 af[4], bf[4];
#pragma unroll
                for (int mi = 0; mi < 4; ++mi)
                    af[mi] = *(const short8*)(wp + ((long)mi * 16 * NTAP + tap) * C_INN);
#pragma unroll
                for (int ni = 0; ni < 4; ++ni) {
                    int g  = wn * 4 + ni;
                    int px = ((g >> 1) + kh) * 34 + (g & 1) * 16 + col + kw;
                    bf[ni] = *(const short8*)(lX + px * LDX_S + quad * 8);
                }
#pragma unroll
                for (int mi = 0; mi < 4; ++mi)
#pragma unroll
                    for (int ni = 0; ni < 4; ++ni)
                        acc[mi][ni] = __builtin_amdgcn_mfma_f32_16x16x32_bf16(
                            af[mi], bf[ni], acc[mi][ni], 0, 0, 0);
            }
        }
    }

    // ---- epilogue: bias + store (C/D layout: col=lane&15, row=quad*4+reg) ----
#pragma unroll
    for (int mi = 0; mi < 4; ++mi) {
        const floatx4 bv = *(const floatx4*)(bias + mtile * 128 + wm * 64 + mi * 16 + quad * 4);
#pragma unroll
        for (int ni = 0; ni < 4; ++ni) {
            int n  = wn * 64 + ni * 16 + col;
            int ph = n >> 5, pw = n & 31;
            if (w0 + pw < W_N) {
#pragma unroll
                for (int r = 0; r < 4; ++r) {
                    int m = mtile * 128 + wm * 64 + mi * 16 + quad * 4 + r;
                    out[(((long)b * C_OUTN + m) * T_N + t) * HW_N + (h0 + ph) * W_N + (w0 + pw)]
                        = acc[mi][ni][r] + bv[r];
                }
            }
        }
    }
}

extern "C" void kernel_launch(void* const* d_in, const int* in_sizes, int n_in,
                              void* d_out, int out_size, void* d_ws, size_t ws_size,
                              hipStream_t stream) {
    const float* x      = (const float*)d_in[0];
    const float* alpha  = (const float*)d_in[1];
    const float* weight = (const float*)d_in[2];
    const float* bias   = (const float*)d_in[3];
    float* out = (float*)d_out;

    __hip_bfloat16* wb = (__hip_bfloat16*)d_ws;   // 256*9*256 bf16 = 1.18 MB

    int nprep = C_OUTN * NTAP * C_INN;
    prep_weight<<<(nprep + 255) / 256, 256, 0, stream>>>(weight, wb);

    dim3 grid(2, 28, 32);
    tada_conv<<<grid, 256, 0, stream>>>(x, alpha, wb, bias, out);
}

// Round 3
// 454.533 us; speedup vs baseline: 1.3818x; 1.2856x over previous
//
#include <hip/hip_runtime.h>
#include <hip/hip_bf16.h>

typedef __attribute__((ext_vector_type(8))) short short8;
typedef __attribute__((ext_vector_type(4))) float floatx4;

#define C_INN 256
#define T_N   8
#define H_N   56
#define W_N   56
#define C_OUTN 256
#define HW_N  (H_N * W_N)
#define THW   (T_N * HW_N)
#define NTAP  9
#define LDX_S 40   // bf16 elems per px row (32 + 8 pad)

// -------- prep: weight (C_OUT, C_IN, 1, 3, 3) fp32 -> wb[c_out][tap][c_in] bf16 --------
__global__ void prep_weight(const float* __restrict__ w, __hip_bfloat16* __restrict__ wb) {
    int idx = blockIdx.x * blockDim.x + threadIdx.x;
    if (idx >= C_OUTN * NTAP * C_INN) return;
    int ci  = idx % C_INN;
    int tap = (idx / C_INN) % NTAP;
    int o   = idx / (NTAP * C_INN);
    wb[idx] = __float2bfloat16(w[(o * C_INN + ci) * NTAP + tap]);
}

// -------- main: M=64 x N=256 block tile; A(all 9 taps) + X halo in LDS; 2 syncs/cg --------
__global__ __launch_bounds__(256, 2) void tada_conv(
    const float* __restrict__ x, const float* __restrict__ alpha,
    const __hip_bfloat16* __restrict__ wb, const float* __restrict__ bias,
    float* __restrict__ out)
{
    // lA[r][tap][ci32]: offset = r*288 + tap*32 + ci  (= 8*chunk for 16B chunk layout)
    __shared__ __hip_bfloat16 lA[64 * NTAP * 32];     // 36864 B
    __shared__ __hip_bfloat16 lX[340 * LDX_S];        // 27200 B (10h x 34w halo)

    const int tid   = threadIdx.x;
    const int mtile = blockIdx.x;          // 0..3   (c_out tile of 64)
    const int ntile = blockIdx.y;          // 0..13  (7 h-tiles x 2 w-tiles)
    const int bt    = blockIdx.z;          // 0..31
    const int b = bt >> 3, t = bt & 7;
    const int h0 = (ntile % 7) * 8;
    const int w0 = (ntile / 7) * 32;

    const int wn   = tid >> 6;             // wave 0..3 -> px quarter
    const int lane = tid & 63;
    const int col = lane & 15, quad = lane >> 4;

    // X staging decomposition: 8 ci-quads x 32 px-lanes
    const int cil = tid >> 5;   // 0..7
    const int pxl = tid & 31;   // 0..31

    floatx4 acc[4][4];
#pragma unroll
    for (int i = 0; i < 4; ++i)
#pragma unroll
        for (int j = 0; j < 4; ++j)
            acc[i][j] = (floatx4){0.f, 0.f, 0.f, 0.f};

    const long xbase = ((long)b * C_INN) * THW + (long)t * HW_N;
    const int  abase = b * C_INN * T_N + t;

    for (int cg = 0; cg < 8; ++cg) {
        __syncthreads();   // previous cg's lA/lX reads done

        // ---- stage A: 64 c_out x 9 taps x 32 ci, coalesced 16B chunks ----
#pragma unroll
        for (int it = 0; it < 9; ++it) {
            int chunk = it * 256 + tid;            // 0..2303
            int r     = chunk / 36;
            int rem   = chunk - r * 36;
            const short8 v = *(const short8*)(wb +
                ((long)((mtile * 64 + r) * NTAP + (rem >> 2)) << 8) + cg * 32 + (rem & 3) * 8);
            *(short8*)(lA + chunk * 8) = v;
        }

        // ---- stage X halo: 32 ci x 10 h x 34 w, alpha-scaled, bf16 ----
        {
            const int ci0 = cg * 32 + cil * 4;
            const float a0 = alpha[abase + (ci0 + 0) * T_N];
            const float a1 = alpha[abase + (ci0 + 1) * T_N];
            const float a2 = alpha[abase + (ci0 + 2) * T_N];
            const float a3 = alpha[abase + (ci0 + 3) * T_N];
            const float* xc = x + xbase + (long)ci0 * THW;
#pragma unroll
            for (int it = 0; it < 11; ++it) {
                int px = pxl + it * 32;
                if (px < 340) {
                    int hi = px / 34;
                    int wi = px - hi * 34;
                    int hh = h0 - 1 + hi;
                    int ww = w0 - 1 + wi;
                    float v0 = 0.f, v1 = 0.f, v2 = 0.f, v3 = 0.f;
                    if (((unsigned)hh < (unsigned)H_N) && ((unsigned)ww < (unsigned)W_N)) {
                        const float* xp = xc + hh * W_N + ww;
                        v0 = xp[0]       * a0;
                        v1 = xp[THW]     * a1;
                        v2 = xp[2 * THW] * a2;
                        v3 = xp[3 * THW] * a3;
                    }
                    union { __hip_bfloat16 h[4]; unsigned long long u; } pk;
                    pk.h[0] = __float2bfloat16(v0);
                    pk.h[1] = __float2bfloat16(v1);
                    pk.h[2] = __float2bfloat16(v2);
                    pk.h[3] = __float2bfloat16(v3);
                    *reinterpret_cast<unsigned long long*>(&lX[px * LDX_S + cil * 4]) = pk.u;
                }
            }
        }
        __syncthreads();   // lA + lX staged

        // ---- 9 taps, barrier-free: 8 ds_read_b128 + 16 MFMA per tap ----
#pragma unroll
        for (int kh = 0; kh < 3; ++kh) {
#pragma unroll
            for (int kw = 0; kw < 3; ++kw) {
                const int tap = kh * 3 + kw;
                short8 af[4], bf[4];
#pragma unroll
                for (int mi = 0; mi < 4; ++mi)
                    af[mi] = *(const short8*)(lA + (mi * 16 + col) * 288 + tap * 32 + quad * 8);
#pragma unroll
                for (int ni = 0; ni < 4; ++ni) {
                    int g  = wn * 4 + ni;                       // 16-px group 0..15
                    int px = ((g >> 1) + kh) * 34 + (g & 1) * 16 + col + kw;
                    bf[ni] = *(const short8*)(lX + px * LDX_S + quad * 8);
                }
#pragma unroll
                for (int mi = 0; mi < 4; ++mi)
#pragma unroll
                    for (int ni = 0; ni < 4; ++ni)
                        acc[mi][ni] = __builtin_amdgcn_mfma_f32_16x16x32_bf16(
                            af[mi], bf[ni], acc[mi][ni], 0, 0, 0);
            }
        }
    }

    // ---- epilogue: bias + store (C/D layout: col=lane&15, row=quad*4+reg) ----
#pragma unroll
    for (int mi = 0; mi < 4; ++mi) {
        const floatx4 bv = *(const floatx4*)(bias + mtile * 64 + mi * 16 + quad * 4);
#pragma unroll
        for (int ni = 0; ni < 4; ++ni) {
            int n  = wn * 64 + ni * 16 + col;
            int ph = n >> 5, pw = n & 31;
            if (w0 + pw < W_N) {
#pragma unroll
                for (int r = 0; r < 4; ++r) {
                    int m = mtile * 64 + mi * 16 + quad * 4 + r;
                    out[(((long)b * C_OUTN + m) * T_N + t) * HW_N + (h0 + ph) * W_N + (w0 + pw)]
                        = acc[mi][ni][r] + bv[r];
                }
            }
        }
    }
}

extern "C" void kernel_launch(void* const* d_in, const int* in_sizes, int n_in,
                              void* d_out, int out_size, void* d_ws, size_t ws_size,
                              hipStream_t stream) {
    const float* x      = (const float*)d_in[0];
    const float* alpha  = (const float*)d_in[1];
    const float* weight = (const float*)d_in[2];
    const float* bias   = (const float*)d_in[3];
    float* out = (float*)d_out;

    __hip_bfloat16* wb = (__hip_bfloat16*)d_ws;   // 256*9*256 bf16 = 1.18 MB

    int nprep = C_OUTN * NTAP * C_INN;
    prep_weight<<<(nprep + 255) / 256, 256, 0, stream>>>(weight, wb);

    dim3 grid(4, 14, 32);
    tada_conv<<<grid, 256, 0, stream>>>(x, alpha, wb, bias, out);
}